// Round 11
// baseline (2560.819 us; speedup 1.0000x reference)
//
#include <hip/hip_runtime.h>

// Seq2Seq round 15 = r10 (2512us) + three width cuts (same validated lever):
//  - enc_step4: 64-thread blocks (1 wave, 16 gate cols) -> 512/256 blocks.
//  - dec_gates_cell512: 8 waves, wave-pairs split K (Wih-half / Whh-half),
//    LDS partials summed in cell phase. Serial K per wave halved.
//  - up_split4: 4-way K-split (K=256/block, 256 blocks), attn2 sums 4 partials.

typedef unsigned short u16;
typedef __attribute__((ext_vector_type(8))) short bf16x8;
typedef __attribute__((ext_vector_type(4))) float f32x4;

#define DEVFN static __device__ __forceinline__

DEVFN float bf2f(u16 u) {
  unsigned int x = ((unsigned int)u) << 16;
  float f; __builtin_memcpy(&f, &x, 4); return f;
}
DEVFN u16 f2bf(float f) {
  unsigned int x; __builtin_memcpy(&x, &f, 4);
  x = (x + 0x7fffu + ((x >> 16) & 1u)) >> 16;
  return (u16)x;
}
DEVFN float sigf(float x) { return 1.f / (1.f + __expf(-x)); }
DEVFN bf16x8 load8(const u16* p) { return *(const bf16x8*)p; }
DEVFN int clampi(int v, int lo, int hi) { return v < lo ? lo : (v > hi ? hi : v); }

// ---------------------------------------------------------------------------
// Generic MFMA GEMM (64x64 block tile). EPI 0: f32 (+bias). EPI 1: bf16.
// ---------------------------------------------------------------------------
struct GemmArgs {
  const u16* A; int lda; int M;
  const u16* W; int ldw; int N; int K;
  void* out; int ldc;
  const float* bias;
  const float* hk_base; const float* proj_act; const int* actions; int t;
};

template <int EPI>
__global__ __launch_bounds__(256) void gemm_k(GemmArgs g) {
  int lane = threadIdx.x & 63;
  int wave = threadIdx.x >> 6;
  int col = lane & 15, q = lane >> 4;
  int m0 = blockIdx.x * 64 + (wave >> 1) * 32;
  int n0 = blockIdx.y * 64 + (wave & 1) * 32;
  f32x4 acc[2][2] = {};
  int rA[2] = { m0 + col, m0 + 16 + col };
  int rB[2] = { n0 + col, n0 + 16 + col };
  bool gA[2] = { rA[0] < g.M, rA[1] < g.M };
  bool gB[2] = { rB[0] < g.N, rB[1] < g.N };
  const u16* pA[2]; const u16* pB[2];
#pragma unroll
  for (int i = 0; i < 2; i++) {
    pA[i] = g.A + (size_t)(gA[i] ? rA[i] : 0) * g.lda + q * 8;
    pB[i] = g.W + (size_t)(gB[i] ? rB[i] : 0) * g.ldw + q * 8;
  }
  bf16x8 zf = {0,0,0,0,0,0,0,0};
  for (int k = 0; k < g.K; k += 32) {
    bf16x8 a0 = gA[0] ? load8(pA[0] + k) : zf;
    bf16x8 a1 = gA[1] ? load8(pA[1] + k) : zf;
    bf16x8 b0 = gB[0] ? load8(pB[0] + k) : zf;
    bf16x8 b1 = gB[1] ? load8(pB[1] + k) : zf;
    acc[0][0] = __builtin_amdgcn_mfma_f32_16x16x32_bf16(a0, b0, acc[0][0], 0, 0, 0);
    acc[0][1] = __builtin_amdgcn_mfma_f32_16x16x32_bf16(a0, b1, acc[0][1], 0, 0, 0);
    acc[1][0] = __builtin_amdgcn_mfma_f32_16x16x32_bf16(a1, b0, acc[1][0], 0, 0, 0);
    acc[1][1] = __builtin_amdgcn_mfma_f32_16x16x32_bf16(a1, b1, acc[1][1], 0, 0, 0);
  }
#pragma unroll
  for (int mi = 0; mi < 2; mi++)
#pragma unroll
    for (int ni = 0; ni < 2; ni++)
#pragma unroll
      for (int r = 0; r < 4; r++) {
        int m = m0 + mi * 16 + q * 4 + r;
        int n = n0 + ni * 16 + col;
        if (m >= g.M || n >= g.N) continue;
        float v = acc[mi][ni][r];
        if constexpr (EPI == 0) {
          if (g.bias) v += g.bias[n];
          ((float*)g.out)[(size_t)m * g.ldc + n] = v;
        } else {
          ((u16*)g.out)[(size_t)m * g.ldc + n] = f2bf(v);
        }
      }
}

// ---------------------------------------------------------------------------
// 32x32-block-tile MFMA GEMM (r7/r8 validated). EPI 0 / EPI 2 (hk).
// ---------------------------------------------------------------------------
template <int EPI>
__global__ __launch_bounds__(256) void gemm32_k(GemmArgs g) {
  int lane = threadIdx.x & 63;
  int wave = threadIdx.x >> 6;
  int col = lane & 15, q = lane >> 4;
  int m0 = blockIdx.x * 32 + (wave >> 1) * 16;
  int n0 = blockIdx.y * 32 + (wave & 1) * 16;
  f32x4 acc = {};
  int rA = m0 + col, rB = n0 + col;
  bool gA = rA < g.M, gB = rB < g.N;
  const u16* pA = g.A + (size_t)(gA ? rA : 0) * g.lda + q * 8;
  const u16* pB = g.W + (size_t)(gB ? rB : 0) * g.ldw + q * 8;
  bf16x8 zf = {0,0,0,0,0,0,0,0};
  for (int k = 0; k < g.K; k += 32) {
    bf16x8 a = gA ? load8(pA + k) : zf;
    bf16x8 b = gB ? load8(pB + k) : zf;
    acc = __builtin_amdgcn_mfma_f32_16x16x32_bf16(a, b, acc, 0, 0, 0);
  }
#pragma unroll
  for (int r = 0; r < 4; r++) {
    int m = m0 + q * 4 + r;
    int n = n0 + col;
    if (m >= g.M || n >= g.N) continue;
    float v = acc[r];
    if constexpr (EPI == 0) {
      if (g.bias) v += g.bias[n];
      ((float*)g.out)[(size_t)m * g.ldc + n] = v;
    } else {
      int act = clampi(g.actions[m * 32 + g.t], 0, 99);
      v += g.hk_base[m * 512 + n] + g.proj_act[(size_t)act * 512 + n];
      ((u16*)g.out)[(size_t)m * g.ldc + n] = f2bf(tanhf(v));
    }
  }
}

// ---------------------------------------------------------------------------
// u_p 4-way K-split: grid (4, 64). qtr = by>>4 (K-quarter), by&15 -> n tile.
// out: u_p4[qtr][128][512] f32 partials (summed in attn2).
// ---------------------------------------------------------------------------
__global__ __launch_bounds__(256) void up_split4(
    const u16* qbuf, const u16* wp, float* u_p4) {
  int lane = threadIdx.x & 63;
  int wave = threadIdx.x >> 6;
  int col = lane & 15, q = lane >> 4;
  int qtr = blockIdx.y >> 4;
  int by = blockIdx.y & 15;
  int m0 = blockIdx.x * 32 + (wave >> 1) * 16;
  int n0 = by * 32 + (wave & 1) * 16;
  f32x4 acc = {};
  const u16* pA = qbuf + (size_t)(m0 + col) * 1024 + qtr * 256 + q * 8;
  const u16* pB = wp + (size_t)(n0 + col) * 1024 + qtr * 256 + q * 8;
  for (int k = 0; k < 256; k += 32) {
    acc = __builtin_amdgcn_mfma_f32_16x16x32_bf16(load8(pA + k), load8(pB + k), acc, 0, 0, 0);
  }
  float* out = u_p4 + (size_t)qtr * 128 * 512;
#pragma unroll
  for (int r = 0; r < 4; r++) {
    int m = m0 + q * 4 + r;
    int n = n0 + col;
    out[(size_t)m * 512 + n] = acc[r];
  }
}

// ---------------------------------------------------------------------------
// Decoder gates + cell, 512 threads: 8 waves; wave w -> tile (w>>1), khalf
// (w&1). Tile t: 16x16 at (m: t>>1, n: t&1) of the block's 32x32. kh=0: Wih
// over zin[0:512]; kh=1: Whh over zin[512:1024]. LDS partials summed in cell.
// Grid (4, 64) = 256 blocks.
// ---------------------------------------------------------------------------
__global__ __launch_bounds__(512) void dec_gates_cell512(
    const u16* zin_cur, const u16* Wih, const u16* Whh, const float* bias_int,
    float* c_ws, u16* zin_nxt, u16* qbuf, u16* outs, int t) {
  int lane = threadIdx.x & 63, wave = threadIdx.x >> 6;
  int col = lane & 15, q = lane >> 4;
  int tile = wave >> 1, kh = wave & 1;
  int m0 = blockIdx.x * 32 + (tile >> 1) * 16;
  int n0 = blockIdx.y * 32 + (tile & 1) * 16;
  f32x4 acc = {};
  int r = n0 + col;
  int src = (r & 3) * 512 + (r >> 2);
  const u16* pA = zin_cur + (size_t)(m0 + col) * 1024 + kh * 512 + q * 8;
  const u16* pW = (kh ? Whh : Wih) + (size_t)src * 512 + q * 8;
  for (int k = 0; k < 512; k += 32) {
    acc = __builtin_amdgcn_mfma_f32_16x16x32_bf16(load8(pA + k), load8(pW + k), acc, 0, 0, 0);
  }
  __shared__ float ls[2][32][36];
#pragma unroll
  for (int rr = 0; rr < 4; rr++) {
    int ml = (tile >> 1) * 16 + q * 4 + rr;
    int nl = (tile & 1) * 16 + col;
    ls[kh][ml][nl] = acc[rr];
  }
  __syncthreads();
  // cell: 256 cells (32 m x 8 j), threads 0..255
  if (threadIdx.x < 256) {
    int m = threadIdx.x & 31, jloc = threadIdx.x >> 5;
    int gm = blockIdx.x * 32 + m;
    int j = blockIdx.y * 8 + jloc;
    int base = jloc * 4;
    float gi = ls[0][m][base + 0] + ls[1][m][base + 0] + bias_int[blockIdx.y * 32 + base + 0];
    float gf = ls[0][m][base + 1] + ls[1][m][base + 1] + bias_int[blockIdx.y * 32 + base + 1];
    float gg = ls[0][m][base + 2] + ls[1][m][base + 2] + bias_int[blockIdx.y * 32 + base + 2];
    float go = ls[0][m][base + 3] + ls[1][m][base + 3] + bias_int[blockIdx.y * 32 + base + 3];
    float cn = sigf(gf) * c_ws[gm * 512 + j] + sigf(gi) * tanhf(gg);
    c_ws[gm * 512 + j] = cn;
    float hn = sigf(go) * tanhf(cn);
    u16 hb = f2bf(hn);
    zin_nxt[(size_t)gm * 1024 + 512 + j] = hb;
    qbuf[(size_t)gm * 1024 + j] = hb;
    outs[((size_t)gm * 32 + t) * 512 + j] = hb;
  }
}

// ---------------------------------------------------------------------------
// prep kernels
// ---------------------------------------------------------------------------
struct CvtJob { const float* src; u16* dst; int R; int C; int ld; int c0; int tr; int blk0; };
struct CvtJobs { CvtJob j[15]; int njobs; };

__global__ void cvt_all(CvtJobs a) {
  int bid = blockIdx.x;
  int ji = 0;
  while (ji + 1 < a.njobs && bid >= a.j[ji + 1].blk0) ji++;
  CvtJob jb = a.j[ji];
  int idx = (bid - jb.blk0) * 256 + threadIdx.x;
  int n = jb.R * jb.C;
  if (idx >= n) return;
  int r = idx / jb.C, c = idx - r * jb.C;
  float v = jb.src[(size_t)r * jb.ld + jb.c0 + c];
  if (jb.tr) jb.dst[(size_t)c * jb.R + r] = f2bf(v);
  else jb.dst[idx] = f2bf(v);
}

// fused: bias_f | bias_b | bwbd | bh2a | bdecint | dec_init
__global__ void prep_small(
    const float* bih_f, const float* bhh_f, float* bias_f,
    const float* bih_b, const float* bhh_b, float* bias_b,
    const float* Wbd_b, float* bwbd,
    const float* h2a_b, float* bh2a,
    const float* dec_bih, const float* dec_bhh, float* bdecint,
    const float* h0, const float* c0, u16* zin0, u16* qbuf, float* c_ws) {
  int i = blockIdx.x * 256 + threadIdx.x;
  if (i < 1024) bias_f[i] = bih_f[i] + bhh_f[i];
  else if (i < 2048) { int k = i - 1024; bias_b[k] = bih_b[k] + bhh_b[k]; }
  else if (i < 2560) { int k = i - 2048; bwbd[k] = Wbd_b[k]; }
  else if (i < 2660) { int k = i - 2560; bh2a[k] = h2a_b[k]; }
  else if (i < 4708) {
    int r = i - 2660;
    int j = r >> 2, gg = r & 3;
    bdecint[r] = dec_bih[gg * 512 + j] + dec_bhh[gg * 512 + j];
  } else if (i < 4708 + 128 * 512) {
    int k = i - 4708;
    int b = k >> 9, d = k & 511;
    u16 hv = f2bf(h0[k]);
    zin0[(size_t)b * 1024 + 512 + d] = hv;
    qbuf[(size_t)b * 1024 + d] = hv;
    c_ws[k] = c0[k];
  }
}

__global__ void wsum_build(const float* Wbd, u16* Wsum) {
  int idx = blockIdx.x * 256 + threadIdx.x; // 512*896
  int n = idx / 896, j = idx % 896;
  int c1 = (j < 448) ? (1024 + j) : (1920 + (j - 448));
  int c2 = c1 + 448;
  Wsum[idx] = f2bf(Wbd[(size_t)n * 2944 + c1] + Wbd[(size_t)n * 2944 + c2]);
}

// ---------------------------------------------------------------------------
// Env encoder (r0 verbatim)
// ---------------------------------------------------------------------------
__global__ __launch_bounds__(256) void env_encode(
    const int* cur_env, const int* ini_env,
    const float* color_emb, const float* pos_emb,
    const float* wih, const float* whh, const float* bih, const float* bhh,
    u16* ctx_cat) {
  __shared__ float s_wih[128 * 33], s_whh[128 * 33], s_b[128], s_col[7 * 32];
  __shared__ float h_lds[8][33];
  int tid = threadIdx.x;
  for (int i = tid; i < 128 * 32; i += 256) {
    int r = i >> 5, k2 = i & 31;
    s_wih[r * 33 + k2] = wih[i];
    s_whh[r * 33 + k2] = whh[i];
  }
  for (int i = tid; i < 128; i += 256) s_b[i] = bih[i] + bhh[i];
  for (int i = tid; i < 224; i += 256) s_col[i] = color_emb[i];
  int sl = tid >> 5, j = tid & 31;
  int gseq = blockIdx.x * 8 + sl;
  int e = gseq / 896, rem = gseq % 896;
  int b = rem / 7, p = rem % 7;
  const int* env = e ? ini_env : cur_env;
  int eoff = e ? 0 : 448;
  h_lds[sl][j] = 0.f;
  __syncthreads();
  float cj = 0.f, hj = 0.f;
  for (int st = 0; st < 4; st++) {
    int tok = clampi(env[b * 35 + p * 5 + 1 + st], 0, 6);
    const float* x = &s_col[tok * 32];
    float pi = s_b[j], pf = s_b[32 + j], pg = s_b[64 + j], po = s_b[96 + j];
    for (int k = 0; k < 32; k++) {
      float xk = x[k], hk = h_lds[sl][k];
      pi += s_wih[j * 33 + k] * xk + s_whh[j * 33 + k] * hk;
      pf += s_wih[(32 + j) * 33 + k] * xk + s_whh[(32 + j) * 33 + k] * hk;
      pg += s_wih[(64 + j) * 33 + k] * xk + s_whh[(64 + j) * 33 + k] * hk;
      po += s_wih[(96 + j) * 33 + k] * xk + s_whh[(96 + j) * 33 + k] * hk;
    }
    cj = sigf(pf) * cj + sigf(pi) * tanhf(pg);
    hj = sigf(po) * tanhf(cj);
    __syncthreads();
    h_lds[sl][j] = hj;
    __syncthreads();
  }
  size_t base = (size_t)b * 896 + eoff + p * 64;
  ctx_cat[base + j] = f2bf(pos_emb[p * 32 + j]);
  ctx_cat[base + 32 + j] = f2bf(hj);
}

// ---------------------------------------------------------------------------
// Encoder step v4: 64-thread blocks (1 wave, 16 gate cols x 4 gates).
// Grid: nchains * 128 blocks (sgrp 0..7 x jq 0..15).
// ---------------------------------------------------------------------------
#define HBUF ((size_t)4 * 128 * 256)
__global__ __launch_bounds__(64) void enc_step4(
    int t, int chainbase,
    const int* ins_tok, const int* his_tok,
    const float* projE_f, const float* projE_b,
    const u16* whh_f, const u16* whh_b,
    const float* bias_f, const float* bias_b,
    u16* h_enc, float* c_enc,
    u16* ins_enc, u16* his_enc) {
  int chain = chainbase + (blockIdx.x >> 7);
  int sub = blockIdx.x & 127;
  int sgrp = sub >> 4, jq = sub & 15;
  int lane = threadIdx.x & 63;
  int col = lane & 15, q = lane >> 4;
  int dir = chain & 1, his = chain >> 1;
  int L = his ? 128 : 64;
  const int* toks = his ? his_tok : ins_tok;
  int t_x = dir ? (L - 1 - t) : t;
  const float* projE = dir ? projE_b : projE_f;
  const u16* whh = dir ? whh_b : whh_f;
  const float* bias = dir ? bias_b : bias_f;
  const u16* h_rd = h_enc + ((size_t)((t & 1) ^ 1)) * HBUF + (size_t)chain * 128 * 256;
  u16* h_wr = h_enc + ((size_t)(t & 1)) * HBUF + (size_t)chain * 128 * 256;
  float* c_g = c_enc + (size_t)chain * 128 * 256;
  u16* out = his ? his_enc : ins_enc;

  int jw = jq * 16;
  f32x4 acc[4] = {};
  if (t > 0) {
    const u16* hrow = h_rd + (size_t)(sgrp * 16 + col) * 256 + q * 8;
    const u16* wrow[4];
#pragma unroll
    for (int G = 0; G < 4; G++) wrow[G] = whh + (size_t)(G * 256 + jw + col) * 256 + q * 8;
    for (int k = 0; k < 256; k += 32) {
      bf16x8 a = load8(hrow + k);
#pragma unroll
      for (int G = 0; G < 4; G++) {
        bf16x8 bb = load8(wrow[G] + k);
        acc[G] = __builtin_amdgcn_mfma_f32_16x16x32_bf16(a, bb, acc[G], 0, 0, 0);
      }
    }
  }
  int j = jw + col;
  float bi = bias[j], bf = bias[256 + j], bg = bias[512 + j], bo = bias[768 + j];
#pragma unroll
  for (int r = 0; r < 4; r++) {
    int s = q * 4 + r;
    int b = sgrp * 16 + s;
    int tok = clampi(toks[b * L + t_x], 0, 1999);
    const float* px = projE + (size_t)tok * 1024;
    float pi = acc[0][r] + px[j] + bi;
    float pf = acc[1][r] + px[256 + j] + bf;
    float pg = acc[2][r] + px[512 + j] + bg;
    float po = acc[3][r] + px[768 + j] + bo;
    float cold = (t > 0) ? c_g[b * 256 + j] : 0.f;
    float cn = sigf(pf) * cold + sigf(pi) * tanhf(pg);
    float hn = sigf(po) * tanhf(cn);
    c_g[b * 256 + j] = cn;
    u16 hb = f2bf(hn);
    h_wr[b * 256 + j] = hb;
    out[((size_t)b * L + t_x) * 512 + dir * 256 + j] = hb;
  }
}

// ---------------------------------------------------------------------------
// Decoder attention 1 — 512 threads (r10 verbatim).
// ---------------------------------------------------------------------------
__global__ __launch_bounds__(512) void attn1(
    const u16* A_c, const u16* insenc, u16* qattn, u16* qbuf) {
  int b = blockIdx.x, tid = threadIdx.x;
  __shared__ float su[512], red[512], aw[64];
  __shared__ float zacc[8][512];
  su[tid] = bf2f(qbuf[(size_t)b * 1024 + tid]);
  __syncthreads();
  {
    int l = tid >> 3, part = tid & 7;
    const u16* row = A_c + ((size_t)b * 64 + l) * 512 + part * 64;
    float s = 0.f;
    for (int k = 0; k < 64; k += 8) {
      bf16x8 v = load8(row + k);
#pragma unroll
      for (int e = 0; e < 8; e++) s += bf2f((u16)v[e]) * su[part * 64 + k + e];
    }
    red[tid] = s;
  }
  __syncthreads();
  if (tid < 64) {
    float sc = 0.f;
#pragma unroll
    for (int i = 0; i < 8; i++) sc += red[tid * 8 + i];
    float m = sc;
    for (int off = 32; off > 0; off >>= 1) m = fmaxf(m, __shfl_xor(m, off));
    float e = __expf(sc - m);
    float sm = e;
    for (int off = 32; off > 0; off >>= 1) sm += __shfl_xor(sm, off);
    aw[tid] = e / sm;
  }
  __syncthreads();
  {
    int part = tid >> 6, chunk = tid & 63;
    float a[8] = {};
    for (int l = part * 8; l < part * 8 + 8; l++) {
      bf16x8 v = load8(insenc + ((size_t)b * 64 + l) * 512 + chunk * 8);
      float w = aw[l];
#pragma unroll
      for (int e = 0; e < 8; e++) a[e] += w * bf2f((u16)v[e]);
    }
#pragma unroll
    for (int e = 0; e < 8; e++) zacc[part][chunk * 8 + e] = a[e];
  }
  __syncthreads();
  {
    float z = zacc[0][tid] + zacc[1][tid] + zacc[2][tid] + zacc[3][tid]
            + zacc[4][tid] + zacc[5][tid] + zacc[6][tid] + zacc[7][tid];
    u16 zb = f2bf(z);
    qattn[(size_t)b * 1024 + tid] = zb;
    qbuf[(size_t)b * 1024 + 512 + tid] = zb;
  }
}

// ---------------------------------------------------------------------------
// Decoder attention 2 — 512 threads; u_p from 4 K-split partials.
// ---------------------------------------------------------------------------
__global__ __launch_bounds__(512) void attn2(
    const float* u_p4, const u16* hisenc, u16* qattn) {
  int b = blockIdx.x, tid = threadIdx.x;
  __shared__ float su[512], red[512], aw[128], mr[2];
  __shared__ float zacc[8][512];
  su[tid] = u_p4[(size_t)b * 512 + tid] + u_p4[65536 + (size_t)b * 512 + tid]
          + u_p4[131072 + (size_t)b * 512 + tid] + u_p4[196608 + (size_t)b * 512 + tid];
  __syncthreads();
  {
    int l = tid >> 2, part = tid & 3;
    const u16* row = hisenc + ((size_t)b * 128 + l) * 512 + part * 128;
    float s = 0.f;
    for (int k = 0; k < 128; k += 8) {
      bf16x8 v = load8(row + k);
#pragma unroll
      for (int e = 0; e < 8; e++) s += bf2f((u16)v[e]) * su[part * 128 + k + e];
    }
    red[tid] = s;
  }
  __syncthreads();
  float sc = 0.f;
  if (tid < 128) sc = red[tid * 4] + red[tid * 4 + 1] + red[tid * 4 + 2] + red[tid * 4 + 3];
  __syncthreads();
  if (tid < 128) red[tid] = sc;
  __syncthreads();
  if (tid < 64) {
    float m = fmaxf(red[tid], red[tid + 64]);
    for (int off = 32; off > 0; off >>= 1) m = fmaxf(m, __shfl_xor(m, off));
    if (tid == 0) mr[0] = m;
  }
  __syncthreads();
  float ex = 0.f;
  if (tid < 128) { ex = __expf(sc - mr[0]); red[tid] = ex; }
  __syncthreads();
  if (tid < 64) {
    float s2 = red[tid] + red[tid + 64];
    for (int off = 32; off > 0; off >>= 1) s2 += __shfl_xor(s2, off);
    if (tid == 0) mr[1] = s2;
  }
  __syncthreads();
  if (tid < 128) aw[tid] = ex / mr[1];
  __syncthreads();
  {
    int part = tid >> 6, chunk = tid & 63;
    float a[8] = {};
    for (int l = part * 16; l < part * 16 + 16; l++) {
      bf16x8 v = load8(hisenc + ((size_t)b * 128 + l) * 512 + chunk * 8);
      float w = aw[l];
#pragma unroll
      for (int e = 0; e < 8; e++) a[e] += w * bf2f((u16)v[e]);
    }
#pragma unroll
    for (int e = 0; e < 8; e++) zacc[part][chunk * 8 + e] = a[e];
  }
  __syncthreads();
  {
    float z = zacc[0][tid] + zacc[1][tid] + zacc[2][tid] + zacc[3][tid]
            + zacc[4][tid] + zacc[5][tid] + zacc[6][tid] + zacc[7][tid];
    qattn[(size_t)b * 1024 + 512 + tid] = f2bf(z);
  }
}

// ---------------------------------------------------------------------------
extern "C" void kernel_launch(void* const* d_in, const int* in_sizes, int n_in,
                              void* d_out, int out_size, void* d_ws, size_t ws_size,
                              hipStream_t stream) {
  const int* ins_tok = (const int*)d_in[0];
  const int* his_tok = (const int*)d_in[1];
  const int* actions = (const int*)d_in[2];
  const int* cur_env = (const int*)d_in[3];
  const int* ini_env = (const int*)d_in[4];
  const float* enc_emb = (const float*)d_in[5];
  const float* Wih_f = (const float*)d_in[6];
  const float* Whh_f = (const float*)d_in[7];
  const float* bih_f = (const float*)d_in[8];
  const float* bhh_f = (const float*)d_in[9];
  const float* Wih_b = (const float*)d_in[10];
  const float* Whh_b = (const float*)d_in[11];
  const float* bih_b = (const float*)d_in[12];
  const float* bhh_b = (const float*)d_in[13];
  const float* color_emb = (const float*)d_in[14];
  const float* pos_emb = (const float*)d_in[15];
  const float* ws_Wih = (const float*)d_in[16];
  const float* ws_Whh = (const float*)d_in[17];
  const float* ws_bih = (const float*)d_in[18];
  const float* ws_bhh = (const float*)d_in[19];
  const float* act_emb = (const float*)d_in[20];
  const float* W_c = (const float*)d_in[21];
  const float* W_p = (const float*)d_in[22];
  // d_in[23..26] are mathematically dead (uniform softmax over broadcast rows).
  const float* Wbd_W = (const float*)d_in[27];
  const float* Wbd_b = (const float*)d_in[28];
  const float* dec_Wih = (const float*)d_in[29];
  const float* dec_Whh = (const float*)d_in[30];
  const float* dec_bih = (const float*)d_in[31];
  const float* dec_bhh = (const float*)d_in[32];
  const float* h2a_W = (const float*)d_in[33];
  const float* h2a_b = (const float*)d_in[34];
  const float* h0 = (const float*)d_in[35];
  const float* c0 = (const float*)d_in[36];
  (void)in_sizes; (void)n_in; (void)out_size; (void)ws_size;

  char* ws = (char*)d_ws;
  size_t off = 0;
  auto alloc = [&](size_t bytes) -> char* {
    char* p = ws + off;
    off = (off + bytes + 255) & ~(size_t)255;
    return p;
  };
  u16* insenc   = (u16*)alloc(8192ull * 512 * 2);
  u16* hisenc   = (u16*)alloc(16384ull * 512 * 2);
  u16* outs     = (u16*)alloc(4096ull * 512 * 2);
  u16* Wsum     = (u16*)alloc(512ull * 896 * 2);
  u16* h_enc    = (u16*)alloc(2 * HBUF * 2);
  float* c_enc  = (float*)alloc(4ull * 128 * 256 * 4);
  float* projact= (float*)alloc(100ull * 512 * 4);
  float* bias_f = (float*)alloc(1024 * 4);
  float* bias_b = (float*)alloc(1024 * 4);
  float* bdecint= (float*)alloc(2048 * 4);
  float* bwbd   = (float*)alloc(512 * 4);
  float* bh2a   = (float*)alloc(128 * 4);
  u16* ctxcat   = (u16*)alloc(128ull * 896 * 2);
  float* hkbase = (float*)alloc(128ull * 512 * 4);
  float* u_p4   = (float*)alloc(4ull * 128 * 512 * 4);  // 4 K-split partials
  u16* qbuf     = (u16*)alloc(128ull * 1024 * 2);
  u16* qattn    = (u16*)alloc(128ull * 1024 * 2);
  u16* zin      = (u16*)alloc(2ull * 128 * 1024 * 2);
  float* c_dec  = (float*)alloc(128ull * 512 * 4);
  float* projE_f = (float*)alloc(2000ull * 1024 * 4);
  float* projE_b = (float*)alloc(2000ull * 1024 * 4);
  u16* A_c      = (u16*)alloc(8192ull * 512 * 2);
  // bf16 weight copies
  u16* emb_bf   = (u16*)alloc(2000ull * 128 * 2);
  u16* wihf_bf  = (u16*)alloc(1024ull * 128 * 2);
  u16* wihb_bf  = (u16*)alloc(1024ull * 128 * 2);
  u16* whhf_bf  = (u16*)alloc(1024ull * 256 * 2);
  u16* whhb_bf  = (u16*)alloc(1024ull * 256 * 2);
  u16* act_bf   = (u16*)alloc(100ull * 128 * 2);
  u16* wcT_bf   = (u16*)alloc(512ull * 512 * 2);
  u16* wp_bf    = (u16*)alloc(512ull * 1024 * 2);
  u16* wbd01_bf = (u16*)alloc(512ull * 1024 * 2);
  u16* wbdx_bf  = (u16*)alloc(512ull * 128 * 2);
  u16* dwih_bf  = (u16*)alloc(2048ull * 512 * 2);
  u16* dwhh_bf  = (u16*)alloc(2048ull * 512 * 2);
  u16* h2a_bf   = (u16*)alloc(100ull * 512 * 2);

  // --- all weight conversions in ONE launch ---
  CvtJobs cj{};
  int nb = 0, jn = 0;
  auto addjob = [&](const float* s, u16* d, int R, int C, int ld, int c0c, int tr) {
    cj.j[jn] = { s, d, R, C, ld, c0c, tr, nb };
    nb += (R * C + 255) / 256;
    jn++;
  };
  addjob(enc_emb, emb_bf, 2000, 128, 128, 0, 0);
  addjob(Wih_f, wihf_bf, 1024, 128, 128, 0, 0);
  addjob(Wih_b, wihb_bf, 1024, 128, 128, 0, 0);
  addjob(Whh_f, whhf_bf, 1024, 256, 256, 0, 0);
  addjob(Whh_b, whhb_bf, 1024, 256, 256, 0, 0);
  addjob(act_emb, act_bf, 100, 128, 128, 0, 0);
  addjob(W_c, wcT_bf, 512, 512, 512, 0, 1);   // transposed
  addjob(W_p, wp_bf, 512, 1024, 1024, 0, 0);
  addjob(Wbd_W, wbd01_bf, 512, 1024, 2944, 0, 0);
  addjob(Wbd_W, wbdx_bf, 512, 128, 2944, 2816, 0);
  addjob(dec_Wih, dwih_bf, 2048, 512, 512, 0, 0);
  addjob(dec_Whh, dwhh_bf, 2048, 512, 512, 0, 0);
  addjob(h2a_W, h2a_bf, 100, 512, 512, 0, 0);
  cj.njobs = jn;
  cvt_all<<<nb, 256, 0, stream>>>(cj);

  // --- fused bias prep + dec_init ---
  prep_small<<<(4708 + 128 * 512 + 255) / 256, 256, 0, stream>>>(
      bih_f, bhh_f, bias_f, bih_b, bhh_b, bias_b,
      Wbd_b, bwbd, h2a_b, bh2a, dec_bih, dec_bhh, bdecint,
      h0, c0, zin, qbuf, c_dec);
  wsum_build<<<1792, 256, 0, stream>>>(Wbd_W, Wsum);

  // --- projE tables ---
  {
    GemmArgs ge = {};
    ge.A = emb_bf; ge.lda = 128; ge.M = 2000; ge.W = wihf_bf; ge.ldw = 128;
    ge.N = 1024; ge.K = 128; ge.out = projE_f; ge.ldc = 1024;
    gemm_k<0><<<dim3(32, 16), 256, 0, stream>>>(ge);
    ge.W = wihb_bf; ge.out = projE_b;
    gemm_k<0><<<dim3(32, 16), 256, 0, stream>>>(ge);
  }

  // --- proj_act = act_emb @ Wbd_x^T + Wbd_b ---
  GemmArgs gp = {};
  gp.A = act_bf; gp.lda = 128; gp.M = 100; gp.W = wbdx_bf; gp.ldw = 128;
  gp.N = 512; gp.K = 128; gp.out = projact; gp.ldc = 512; gp.bias = bwbd;
  gemm_k<0><<<dim3(2, 8), 256, 0, stream>>>(gp);

  // --- env encode + hk_base ---
  env_encode<<<224, 256, 0, stream>>>(cur_env, ini_env, color_emb, pos_emb,
                                      ws_Wih, ws_Whh, ws_bih, ws_bhh, ctxcat);
  GemmArgs gb = {};
  gb.A = ctxcat; gb.lda = 896; gb.M = 128; gb.W = Wsum; gb.ldw = 896;
  gb.N = 512; gb.K = 896; gb.out = hkbase; gb.ldc = 512;
  gemm_k<0><<<dim3(2, 8), 256, 0, stream>>>(gb);

  // --- encoder: 128 sequential steps, 64-thread blocks ---
  for (int t = 0; t < 128; t++) {
    int cb = (t < 64) ? 0 : 2;
    int nbk = (t < 64) ? 512 : 256;
    enc_step4<<<nbk, 64, 0, stream>>>(t, cb, ins_tok, his_tok,
                                      projE_f, projE_b, whhf_bf, whhb_bf,
                                      bias_f, bias_b, h_enc, c_enc,
                                      insenc, hisenc);
  }

  // --- A_c = insenc @ W_c ---
  {
    GemmArgs ga = {};
    ga.A = insenc; ga.lda = 512; ga.M = 8192; ga.W = wcT_bf; ga.ldw = 512;
    ga.N = 512; ga.K = 512; ga.out = A_c; ga.ldc = 512;
    gemm_k<1><<<dim3(128, 8), 256, 0, stream>>>(ga);
  }

  // --- decoder: 5 dispatches/step ---
  for (int t = 0; t < 32; t++) {
    u16* zin_cur = zin + (size_t)(t & 1) * 128 * 1024;
    u16* zin_nxt = zin + (size_t)((t + 1) & 1) * 128 * 1024;
    attn1<<<128, 512, 0, stream>>>(A_c, insenc, qattn, qbuf);
    up_split4<<<dim3(4, 64), 256, 0, stream>>>(qbuf, wp_bf, u_p4);
    attn2<<<128, 512, 0, stream>>>(u_p4, hisenc, qattn);
    GemmArgs gh = {};
    gh.A = qattn; gh.lda = 1024; gh.M = 128; gh.W = wbd01_bf; gh.ldw = 1024;
    gh.N = 512; gh.K = 1024; gh.out = zin_cur; gh.ldc = 1024;
    gh.hk_base = hkbase; gh.proj_act = projact; gh.actions = actions; gh.t = t;
    gemm32_k<2><<<dim3(4, 16), 256, 0, stream>>>(gh);
    dec_gates_cell512<<<dim3(4, 64), 512, 0, stream>>>(
        zin_cur, dwih_bf, dwhh_bf, bdecint, c_dec, zin_nxt, qbuf, outs, t);
  }

  // --- logits (f32 out): 512 blocks ---
  GemmArgs gl = {};
  gl.A = outs; gl.lda = 512; gl.M = 4096; gl.W = h2a_bf; gl.ldw = 512;
  gl.N = 100; gl.K = 512; gl.out = d_out; gl.ldc = 100; gl.bias = bh2a;
  gemm32_k<0><<<dim3(128, 4), 256, 0, stream>>>(gl);
}

// Round 12
// 2549.733 us; speedup vs baseline: 1.0043x; 1.0043x over previous
//
#include <hip/hip_runtime.h>

// Seq2Seq round 16 = EXACT REVERT to r10 (2512us, best verified).
// r11's three width cuts (64-thr encoder, 8-wave gates, 4-way u_p) were
// collectively -2%: the widening lever is exhausted (phases at 16-32 serial
// MFMAs; split overhead >= savings). Structure ledger:
//  - persistent kernels: disproven (r6: agent-scope barriers flush per-XCD L2,
//    16MB/step refetch; r2/r3: per-block weight re-streaming).
//  - per-thread GEMV fusions: disproven (r5).
//  - launch-based + widened tiles + hoisted invariants (projE, A_c): optimal
//    found configuration. ~300 dispatches at the dispatch/latency floor.

typedef unsigned short u16;
typedef __attribute__((ext_vector_type(8))) short bf16x8;
typedef __attribute__((ext_vector_type(4))) float f32x4;

#define DEVFN static __device__ __forceinline__

DEVFN float bf2f(u16 u) {
  unsigned int x = ((unsigned int)u) << 16;
  float f; __builtin_memcpy(&f, &x, 4); return f;
}
DEVFN u16 f2bf(float f) {
  unsigned int x; __builtin_memcpy(&x, &f, 4);
  x = (x + 0x7fffu + ((x >> 16) & 1u)) >> 16;
  return (u16)x;
}
DEVFN float sigf(float x) { return 1.f / (1.f + __expf(-x)); }
DEVFN bf16x8 load8(const u16* p) { return *(const bf16x8*)p; }
DEVFN int clampi(int v, int lo, int hi) { return v < lo ? lo : (v > hi ? hi : v); }

// ---------------------------------------------------------------------------
// Generic MFMA GEMM (64x64 block tile). EPI 0: f32 (+bias). EPI 1: bf16.
// ---------------------------------------------------------------------------
struct GemmArgs {
  const u16* A; int lda; int M;
  const u16* W; int ldw; int N; int K;
  void* out; int ldc;
  const float* bias;
  const float* hk_base; const float* proj_act; const int* actions; int t;
};

template <int EPI>
__global__ __launch_bounds__(256) void gemm_k(GemmArgs g) {
  int lane = threadIdx.x & 63;
  int wave = threadIdx.x >> 6;
  int col = lane & 15, q = lane >> 4;
  int m0 = blockIdx.x * 64 + (wave >> 1) * 32;
  int n0 = blockIdx.y * 64 + (wave & 1) * 32;
  f32x4 acc[2][2] = {};
  int rA[2] = { m0 + col, m0 + 16 + col };
  int rB[2] = { n0 + col, n0 + 16 + col };
  bool gA[2] = { rA[0] < g.M, rA[1] < g.M };
  bool gB[2] = { rB[0] < g.N, rB[1] < g.N };
  const u16* pA[2]; const u16* pB[2];
#pragma unroll
  for (int i = 0; i < 2; i++) {
    pA[i] = g.A + (size_t)(gA[i] ? rA[i] : 0) * g.lda + q * 8;
    pB[i] = g.W + (size_t)(gB[i] ? rB[i] : 0) * g.ldw + q * 8;
  }
  bf16x8 zf = {0,0,0,0,0,0,0,0};
  for (int k = 0; k < g.K; k += 32) {
    bf16x8 a0 = gA[0] ? load8(pA[0] + k) : zf;
    bf16x8 a1 = gA[1] ? load8(pA[1] + k) : zf;
    bf16x8 b0 = gB[0] ? load8(pB[0] + k) : zf;
    bf16x8 b1 = gB[1] ? load8(pB[1] + k) : zf;
    acc[0][0] = __builtin_amdgcn_mfma_f32_16x16x32_bf16(a0, b0, acc[0][0], 0, 0, 0);
    acc[0][1] = __builtin_amdgcn_mfma_f32_16x16x32_bf16(a0, b1, acc[0][1], 0, 0, 0);
    acc[1][0] = __builtin_amdgcn_mfma_f32_16x16x32_bf16(a1, b0, acc[1][0], 0, 0, 0);
    acc[1][1] = __builtin_amdgcn_mfma_f32_16x16x32_bf16(a1, b1, acc[1][1], 0, 0, 0);
  }
#pragma unroll
  for (int mi = 0; mi < 2; mi++)
#pragma unroll
    for (int ni = 0; ni < 2; ni++)
#pragma unroll
      for (int r = 0; r < 4; r++) {
        int m = m0 + mi * 16 + q * 4 + r;
        int n = n0 + ni * 16 + col;
        if (m >= g.M || n >= g.N) continue;
        float v = acc[mi][ni][r];
        if constexpr (EPI == 0) {
          if (g.bias) v += g.bias[n];
          ((float*)g.out)[(size_t)m * g.ldc + n] = v;
        } else {
          ((u16*)g.out)[(size_t)m * g.ldc + n] = f2bf(v);
        }
      }
}

// ---------------------------------------------------------------------------
// 32x32-block-tile MFMA GEMM (r7/r8 validated). EPI 0 / EPI 2 (hk).
// ---------------------------------------------------------------------------
template <int EPI>
__global__ __launch_bounds__(256) void gemm32_k(GemmArgs g) {
  int lane = threadIdx.x & 63;
  int wave = threadIdx.x >> 6;
  int col = lane & 15, q = lane >> 4;
  int m0 = blockIdx.x * 32 + (wave >> 1) * 16;
  int n0 = blockIdx.y * 32 + (wave & 1) * 16;
  f32x4 acc = {};
  int rA = m0 + col, rB = n0 + col;
  bool gA = rA < g.M, gB = rB < g.N;
  const u16* pA = g.A + (size_t)(gA ? rA : 0) * g.lda + q * 8;
  const u16* pB = g.W + (size_t)(gB ? rB : 0) * g.ldw + q * 8;
  bf16x8 zf = {0,0,0,0,0,0,0,0};
  for (int k = 0; k < g.K; k += 32) {
    bf16x8 a = gA ? load8(pA + k) : zf;
    bf16x8 b = gB ? load8(pB + k) : zf;
    acc = __builtin_amdgcn_mfma_f32_16x16x32_bf16(a, b, acc, 0, 0, 0);
  }
#pragma unroll
  for (int r = 0; r < 4; r++) {
    int m = m0 + q * 4 + r;
    int n = n0 + col;
    if (m >= g.M || n >= g.N) continue;
    float v = acc[r];
    if constexpr (EPI == 0) {
      if (g.bias) v += g.bias[n];
      ((float*)g.out)[(size_t)m * g.ldc + n] = v;
    } else {
      int act = clampi(g.actions[m * 32 + g.t], 0, 99);
      v += g.hk_base[m * 512 + n] + g.proj_act[(size_t)act * 512 + n];
      ((u16*)g.out)[(size_t)m * g.ldc + n] = f2bf(tanhf(v));
    }
  }
}

// ---------------------------------------------------------------------------
// u_p K-split: grid (4, 32). by<16 -> K-half 0; by>=16 -> K-half 1.
// out: u_p2[half][128][512] f32 partials (summed in attn2).
// ---------------------------------------------------------------------------
__global__ __launch_bounds__(256) void up_split(
    const u16* qbuf, const u16* wp, float* u_p2) {
  int lane = threadIdx.x & 63;
  int wave = threadIdx.x >> 6;
  int col = lane & 15, q = lane >> 4;
  int half = blockIdx.y >> 4;
  int by = blockIdx.y & 15;
  int m0 = blockIdx.x * 32 + (wave >> 1) * 16;
  int n0 = by * 32 + (wave & 1) * 16;
  f32x4 acc = {};
  const u16* pA = qbuf + (size_t)(m0 + col) * 1024 + half * 512 + q * 8;
  const u16* pB = wp + (size_t)(n0 + col) * 1024 + half * 512 + q * 8;
  for (int k = 0; k < 512; k += 32) {
    acc = __builtin_amdgcn_mfma_f32_16x16x32_bf16(load8(pA + k), load8(pB + k), acc, 0, 0, 0);
  }
  float* out = u_p2 + (size_t)half * 128 * 512;
#pragma unroll
  for (int r = 0; r < 4; r++) {
    int m = m0 + q * 4 + r;
    int n = n0 + col;
    out[(size_t)m * 512 + n] = acc[r];
  }
}

// ---------------------------------------------------------------------------
// Decoder gates GEMM + fused LSTM cell, 32x32 tiles (r8 verbatim).
// ---------------------------------------------------------------------------
__global__ __launch_bounds__(256) void dec_gates_cell32(
    const u16* zin_cur, const u16* Wih, const u16* Whh, const float* bias_int,
    float* c_ws, u16* zin_nxt, u16* qbuf, u16* outs, int t) {
  int lane = threadIdx.x & 63, wave = threadIdx.x >> 6;
  int col = lane & 15, q = lane >> 4;
  int m0 = blockIdx.x * 32 + (wave >> 1) * 16;
  int n0 = blockIdx.y * 32 + (wave & 1) * 16;
  f32x4 acc = {};
  const u16* pA = zin_cur + (size_t)(m0 + col) * 1024 + q * 8;
  int r = n0 + col;
  int src = (r & 3) * 512 + (r >> 2);
  const u16* pI = Wih + (size_t)src * 512 + q * 8;
  const u16* pH = Whh + (size_t)src * 512 + q * 8;
  for (int k = 0; k < 512; k += 32) {
    acc = __builtin_amdgcn_mfma_f32_16x16x32_bf16(load8(pA + k), load8(pI + k), acc, 0, 0, 0);
  }
  for (int k = 0; k < 512; k += 32) {
    acc = __builtin_amdgcn_mfma_f32_16x16x32_bf16(load8(pA + 512 + k), load8(pH + k), acc, 0, 0, 0);
  }
  __shared__ float ls[32][36];
#pragma unroll
  for (int rr = 0; rr < 4; rr++) {
    int ml = (wave >> 1) * 16 + q * 4 + rr;
    int nl = (wave & 1) * 16 + col;
    ls[ml][nl] = acc[rr] + bias_int[blockIdx.y * 32 + nl];
  }
  __syncthreads();
  int m = threadIdx.x & 31, jloc = threadIdx.x >> 5;
  int gm = blockIdx.x * 32 + m;
  int j = blockIdx.y * 8 + jloc;
  float gi = ls[m][jloc * 4 + 0];
  float gf = ls[m][jloc * 4 + 1];
  float gg = ls[m][jloc * 4 + 2];
  float go = ls[m][jloc * 4 + 3];
  float cn = sigf(gf) * c_ws[gm * 512 + j] + sigf(gi) * tanhf(gg);
  c_ws[gm * 512 + j] = cn;
  float hn = sigf(go) * tanhf(cn);
  u16 hb = f2bf(hn);
  zin_nxt[(size_t)gm * 1024 + 512 + j] = hb;
  qbuf[(size_t)gm * 1024 + j] = hb;
  outs[((size_t)gm * 32 + t) * 512 + j] = hb;
}

// ---------------------------------------------------------------------------
// prep kernels
// ---------------------------------------------------------------------------
struct CvtJob { const float* src; u16* dst; int R; int C; int ld; int c0; int tr; int blk0; };
struct CvtJobs { CvtJob j[15]; int njobs; };

__global__ void cvt_all(CvtJobs a) {
  int bid = blockIdx.x;
  int ji = 0;
  while (ji + 1 < a.njobs && bid >= a.j[ji + 1].blk0) ji++;
  CvtJob jb = a.j[ji];
  int idx = (bid - jb.blk0) * 256 + threadIdx.x;
  int n = jb.R * jb.C;
  if (idx >= n) return;
  int r = idx / jb.C, c = idx - r * jb.C;
  float v = jb.src[(size_t)r * jb.ld + jb.c0 + c];
  if (jb.tr) jb.dst[(size_t)c * jb.R + r] = f2bf(v);
  else jb.dst[idx] = f2bf(v);
}

// fused: bias_f | bias_b | bwbd | bh2a | bdecint | dec_init
__global__ void prep_small(
    const float* bih_f, const float* bhh_f, float* bias_f,
    const float* bih_b, const float* bhh_b, float* bias_b,
    const float* Wbd_b, float* bwbd,
    const float* h2a_b, float* bh2a,
    const float* dec_bih, const float* dec_bhh, float* bdecint,
    const float* h0, const float* c0, u16* zin0, u16* qbuf, float* c_ws) {
  int i = blockIdx.x * 256 + threadIdx.x;
  if (i < 1024) bias_f[i] = bih_f[i] + bhh_f[i];
  else if (i < 2048) { int k = i - 1024; bias_b[k] = bih_b[k] + bhh_b[k]; }
  else if (i < 2560) { int k = i - 2048; bwbd[k] = Wbd_b[k]; }
  else if (i < 2660) { int k = i - 2560; bh2a[k] = h2a_b[k]; }
  else if (i < 4708) {
    int r = i - 2660;
    int j = r >> 2, gg = r & 3;
    bdecint[r] = dec_bih[gg * 512 + j] + dec_bhh[gg * 512 + j];
  } else if (i < 4708 + 128 * 512) {
    int k = i - 4708;
    int b = k >> 9, d = k & 511;
    u16 hv = f2bf(h0[k]);
    zin0[(size_t)b * 1024 + 512 + d] = hv;
    qbuf[(size_t)b * 1024 + d] = hv;
    c_ws[k] = c0[k];
  }
}

__global__ void wsum_build(const float* Wbd, u16* Wsum) {
  int idx = blockIdx.x * 256 + threadIdx.x; // 512*896
  int n = idx / 896, j = idx % 896;
  int c1 = (j < 448) ? (1024 + j) : (1920 + (j - 448));
  int c2 = c1 + 448;
  Wsum[idx] = f2bf(Wbd[(size_t)n * 2944 + c1] + Wbd[(size_t)n * 2944 + c2]);
}

// ---------------------------------------------------------------------------
// Env encoder (r0 verbatim)
// ---------------------------------------------------------------------------
__global__ __launch_bounds__(256) void env_encode(
    const int* cur_env, const int* ini_env,
    const float* color_emb, const float* pos_emb,
    const float* wih, const float* whh, const float* bih, const float* bhh,
    u16* ctx_cat) {
  __shared__ float s_wih[128 * 33], s_whh[128 * 33], s_b[128], s_col[7 * 32];
  __shared__ float h_lds[8][33];
  int tid = threadIdx.x;
  for (int i = tid; i < 128 * 32; i += 256) {
    int r = i >> 5, k2 = i & 31;
    s_wih[r * 33 + k2] = wih[i];
    s_whh[r * 33 + k2] = whh[i];
  }
  for (int i = tid; i < 128; i += 256) s_b[i] = bih[i] + bhh[i];
  for (int i = tid; i < 224; i += 256) s_col[i] = color_emb[i];
  int sl = tid >> 5, j = tid & 31;
  int gseq = blockIdx.x * 8 + sl;
  int e = gseq / 896, rem = gseq % 896;
  int b = rem / 7, p = rem % 7;
  const int* env = e ? ini_env : cur_env;
  int eoff = e ? 0 : 448;
  h_lds[sl][j] = 0.f;
  __syncthreads();
  float cj = 0.f, hj = 0.f;
  for (int st = 0; st < 4; st++) {
    int tok = clampi(env[b * 35 + p * 5 + 1 + st], 0, 6);
    const float* x = &s_col[tok * 32];
    float pi = s_b[j], pf = s_b[32 + j], pg = s_b[64 + j], po = s_b[96 + j];
    for (int k = 0; k < 32; k++) {
      float xk = x[k], hk = h_lds[sl][k];
      pi += s_wih[j * 33 + k] * xk + s_whh[j * 33 + k] * hk;
      pf += s_wih[(32 + j) * 33 + k] * xk + s_whh[(32 + j) * 33 + k] * hk;
      pg += s_wih[(64 + j) * 33 + k] * xk + s_whh[(64 + j) * 33 + k] * hk;
      po += s_wih[(96 + j) * 33 + k] * xk + s_whh[(96 + j) * 33 + k] * hk;
    }
    cj = sigf(pf) * cj + sigf(pi) * tanhf(pg);
    hj = sigf(po) * tanhf(cj);
    __syncthreads();
    h_lds[sl][j] = hj;
    __syncthreads();
  }
  size_t base = (size_t)b * 896 + eoff + p * 64;
  ctx_cat[base + j] = f2bf(pos_emb[p * 32 + j]);
  ctx_cat[base + 32 + j] = f2bf(hj);
}

// ---------------------------------------------------------------------------
// Encoder step v3 (r9/r10 verbatim): 128-thread blocks.
// ---------------------------------------------------------------------------
#define HBUF ((size_t)4 * 128 * 256)
__global__ __launch_bounds__(128) void enc_step3(
    int t, int chainbase,
    const int* ins_tok, const int* his_tok,
    const float* projE_f, const float* projE_b,
    const u16* whh_f, const u16* whh_b,
    const float* bias_f, const float* bias_b,
    u16* h_enc, float* c_enc,
    u16* ins_enc, u16* his_enc) {
  int chain = chainbase + (blockIdx.x >> 6);
  int sub = blockIdx.x & 63;
  int sgrp = sub >> 3, jq = sub & 7;
  int w = threadIdx.x >> 6, lane = threadIdx.x & 63;
  int col = lane & 15, q = lane >> 4;
  int dir = chain & 1, his = chain >> 1;
  int L = his ? 128 : 64;
  const int* toks = his ? his_tok : ins_tok;
  int t_x = dir ? (L - 1 - t) : t;
  const float* projE = dir ? projE_b : projE_f;
  const u16* whh = dir ? whh_b : whh_f;
  const float* bias = dir ? bias_b : bias_f;
  const u16* h_rd = h_enc + ((size_t)((t & 1) ^ 1)) * HBUF + (size_t)chain * 128 * 256;
  u16* h_wr = h_enc + ((size_t)(t & 1)) * HBUF + (size_t)chain * 128 * 256;
  float* c_g = c_enc + (size_t)chain * 128 * 256;
  u16* out = his ? his_enc : ins_enc;

  int jw = jq * 32 + w * 16;
  f32x4 acc[4] = {};
  if (t > 0) {
    const u16* hrow = h_rd + (size_t)(sgrp * 16 + col) * 256 + q * 8;
    const u16* wrow[4];
#pragma unroll
    for (int G = 0; G < 4; G++) wrow[G] = whh + (size_t)(G * 256 + jw + col) * 256 + q * 8;
    for (int k = 0; k < 256; k += 32) {
      bf16x8 a = load8(hrow + k);
#pragma unroll
      for (int G = 0; G < 4; G++) {
        bf16x8 bb = load8(wrow[G] + k);
        acc[G] = __builtin_amdgcn_mfma_f32_16x16x32_bf16(a, bb, acc[G], 0, 0, 0);
      }
    }
  }
  int j = jw + col;
  float bi = bias[j], bf = bias[256 + j], bg = bias[512 + j], bo = bias[768 + j];
#pragma unroll
  for (int r = 0; r < 4; r++) {
    int s = q * 4 + r;
    int b = sgrp * 16 + s;
    int tok = clampi(toks[b * L + t_x], 0, 1999);
    const float* px = projE + (size_t)tok * 1024;
    float pi = acc[0][r] + px[j] + bi;
    float pf = acc[1][r] + px[256 + j] + bf;
    float pg = acc[2][r] + px[512 + j] + bg;
    float po = acc[3][r] + px[768 + j] + bo;
    float cold = (t > 0) ? c_g[b * 256 + j] : 0.f;
    float cn = sigf(pf) * cold + sigf(pi) * tanhf(pg);
    float hn = sigf(po) * tanhf(cn);
    c_g[b * 256 + j] = cn;
    u16 hb = f2bf(hn);
    h_wr[b * 256 + j] = hb;
    out[((size_t)b * L + t_x) * 512 + dir * 256 + j] = hb;
  }
}

// ---------------------------------------------------------------------------
// Decoder attention 1 — 512 threads (r10 verbatim).
// ---------------------------------------------------------------------------
__global__ __launch_bounds__(512) void attn1(
    const u16* A_c, const u16* insenc, u16* qattn, u16* qbuf) {
  int b = blockIdx.x, tid = threadIdx.x;
  __shared__ float su[512], red[512], aw[64];
  __shared__ float zacc[8][512];
  su[tid] = bf2f(qbuf[(size_t)b * 1024 + tid]);
  __syncthreads();
  {
    int l = tid >> 3, part = tid & 7;
    const u16* row = A_c + ((size_t)b * 64 + l) * 512 + part * 64;
    float s = 0.f;
    for (int k = 0; k < 64; k += 8) {
      bf16x8 v = load8(row + k);
#pragma unroll
      for (int e = 0; e < 8; e++) s += bf2f((u16)v[e]) * su[part * 64 + k + e];
    }
    red[tid] = s;
  }
  __syncthreads();
  if (tid < 64) {
    float sc = 0.f;
#pragma unroll
    for (int i = 0; i < 8; i++) sc += red[tid * 8 + i];
    float m = sc;
    for (int off = 32; off > 0; off >>= 1) m = fmaxf(m, __shfl_xor(m, off));
    float e = __expf(sc - m);
    float sm = e;
    for (int off = 32; off > 0; off >>= 1) sm += __shfl_xor(sm, off);
    aw[tid] = e / sm;
  }
  __syncthreads();
  {
    int part = tid >> 6, chunk = tid & 63;
    float a[8] = {};
    for (int l = part * 8; l < part * 8 + 8; l++) {
      bf16x8 v = load8(insenc + ((size_t)b * 64 + l) * 512 + chunk * 8);
      float w = aw[l];
#pragma unroll
      for (int e = 0; e < 8; e++) a[e] += w * bf2f((u16)v[e]);
    }
#pragma unroll
    for (int e = 0; e < 8; e++) zacc[part][chunk * 8 + e] = a[e];
  }
  __syncthreads();
  {
    float z = zacc[0][tid] + zacc[1][tid] + zacc[2][tid] + zacc[3][tid]
            + zacc[4][tid] + zacc[5][tid] + zacc[6][tid] + zacc[7][tid];
    u16 zb = f2bf(z);
    qattn[(size_t)b * 1024 + tid] = zb;
    qbuf[(size_t)b * 1024 + 512 + tid] = zb;
  }
}

// ---------------------------------------------------------------------------
// Decoder attention 2 — 512 threads; u_p from 2 K-split partials.
// ---------------------------------------------------------------------------
__global__ __launch_bounds__(512) void attn2(
    const float* u_p2, const u16* hisenc, u16* qattn) {
  int b = blockIdx.x, tid = threadIdx.x;
  __shared__ float su[512], red[512], aw[128], mr[2];
  __shared__ float zacc[8][512];
  su[tid] = u_p2[(size_t)b * 512 + tid] + u_p2[65536 + (size_t)b * 512 + tid];
  __syncthreads();
  {
    int l = tid >> 2, part = tid & 3;
    const u16* row = hisenc + ((size_t)b * 128 + l) * 512 + part * 128;
    float s = 0.f;
    for (int k = 0; k < 128; k += 8) {
      bf16x8 v = load8(row + k);
#pragma unroll
      for (int e = 0; e < 8; e++) s += bf2f((u16)v[e]) * su[part * 128 + k + e];
    }
    red[tid] = s;
  }
  __syncthreads();
  float sc = 0.f;
  if (tid < 128) sc = red[tid * 4] + red[tid * 4 + 1] + red[tid * 4 + 2] + red[tid * 4 + 3];
  __syncthreads();
  if (tid < 128) red[tid] = sc;
  __syncthreads();
  if (tid < 64) {
    float m = fmaxf(red[tid], red[tid + 64]);
    for (int off = 32; off > 0; off >>= 1) m = fmaxf(m, __shfl_xor(m, off));
    if (tid == 0) mr[0] = m;
  }
  __syncthreads();
  float ex = 0.f;
  if (tid < 128) { ex = __expf(sc - mr[0]); red[tid] = ex; }
  __syncthreads();
  if (tid < 64) {
    float s2 = red[tid] + red[tid + 64];
    for (int off = 32; off > 0; off >>= 1) s2 += __shfl_xor(s2, off);
    if (tid == 0) mr[1] = s2;
  }
  __syncthreads();
  if (tid < 128) aw[tid] = ex / mr[1];
  __syncthreads();
  {
    int part = tid >> 6, chunk = tid & 63;
    float a[8] = {};
    for (int l = part * 16; l < part * 16 + 16; l++) {
      bf16x8 v = load8(hisenc + ((size_t)b * 128 + l) * 512 + chunk * 8);
      float w = aw[l];
#pragma unroll
      for (int e = 0; e < 8; e++) a[e] += w * bf2f((u16)v[e]);
    }
#pragma unroll
    for (int e = 0; e < 8; e++) zacc[part][chunk * 8 + e] = a[e];
  }
  __syncthreads();
  {
    float z = zacc[0][tid] + zacc[1][tid] + zacc[2][tid] + zacc[3][tid]
            + zacc[4][tid] + zacc[5][tid] + zacc[6][tid] + zacc[7][tid];
    qattn[(size_t)b * 1024 + 512 + tid] = f2bf(z);
  }
}

// ---------------------------------------------------------------------------
extern "C" void kernel_launch(void* const* d_in, const int* in_sizes, int n_in,
                              void* d_out, int out_size, void* d_ws, size_t ws_size,
                              hipStream_t stream) {
  const int* ins_tok = (const int*)d_in[0];
  const int* his_tok = (const int*)d_in[1];
  const int* actions = (const int*)d_in[2];
  const int* cur_env = (const int*)d_in[3];
  const int* ini_env = (const int*)d_in[4];
  const float* enc_emb = (const float*)d_in[5];
  const float* Wih_f = (const float*)d_in[6];
  const float* Whh_f = (const float*)d_in[7];
  const float* bih_f = (const float*)d_in[8];
  const float* bhh_f = (const float*)d_in[9];
  const float* Wih_b = (const float*)d_in[10];
  const float* Whh_b = (const float*)d_in[11];
  const float* bih_b = (const float*)d_in[12];
  const float* bhh_b = (const float*)d_in[13];
  const float* color_emb = (const float*)d_in[14];
  const float* pos_emb = (const float*)d_in[15];
  const float* ws_Wih = (const float*)d_in[16];
  const float* ws_Whh = (const float*)d_in[17];
  const float* ws_bih = (const float*)d_in[18];
  const float* ws_bhh = (const float*)d_in[19];
  const float* act_emb = (const float*)d_in[20];
  const float* W_c = (const float*)d_in[21];
  const float* W_p = (const float*)d_in[22];
  // d_in[23..26] are mathematically dead (uniform softmax over broadcast rows).
  const float* Wbd_W = (const float*)d_in[27];
  const float* Wbd_b = (const float*)d_in[28];
  const float* dec_Wih = (const float*)d_in[29];
  const float* dec_Whh = (const float*)d_in[30];
  const float* dec_bih = (const float*)d_in[31];
  const float* dec_bhh = (const float*)d_in[32];
  const float* h2a_W = (const float*)d_in[33];
  const float* h2a_b = (const float*)d_in[34];
  const float* h0 = (const float*)d_in[35];
  const float* c0 = (const float*)d_in[36];
  (void)in_sizes; (void)n_in; (void)out_size; (void)ws_size;

  char* ws = (char*)d_ws;
  size_t off = 0;
  auto alloc = [&](size_t bytes) -> char* {
    char* p = ws + off;
    off = (off + bytes + 255) & ~(size_t)255;
    return p;
  };
  u16* insenc   = (u16*)alloc(8192ull * 512 * 2);
  u16* hisenc   = (u16*)alloc(16384ull * 512 * 2);
  u16* outs     = (u16*)alloc(4096ull * 512 * 2);
  u16* Wsum     = (u16*)alloc(512ull * 896 * 2);
  u16* h_enc    = (u16*)alloc(2 * HBUF * 2);
  float* c_enc  = (float*)alloc(4ull * 128 * 256 * 4);
  float* projact= (float*)alloc(100ull * 512 * 4);
  float* bias_f = (float*)alloc(1024 * 4);
  float* bias_b = (float*)alloc(1024 * 4);
  float* bdecint= (float*)alloc(2048 * 4);
  float* bwbd   = (float*)alloc(512 * 4);
  float* bh2a   = (float*)alloc(128 * 4);
  u16* ctxcat   = (u16*)alloc(128ull * 896 * 2);
  float* hkbase = (float*)alloc(128ull * 512 * 4);
  float* u_p2   = (float*)alloc(2ull * 128 * 512 * 4);  // K-split partials
  u16* qbuf     = (u16*)alloc(128ull * 1024 * 2);     // [h | z_c]
  u16* qattn    = (u16*)alloc(128ull * 1024 * 2);     // [z_c | z_p]
  u16* zin      = (u16*)alloc(2ull * 128 * 1024 * 2); // [hk | h], parity
  float* c_dec  = (float*)alloc(128ull * 512 * 4);
  float* projE_f = (float*)alloc(2000ull * 1024 * 4);
  float* projE_b = (float*)alloc(2000ull * 1024 * 4);
  u16* A_c      = (u16*)alloc(8192ull * 512 * 2);
  // bf16 weight copies
  u16* emb_bf   = (u16*)alloc(2000ull * 128 * 2);
  u16* wihf_bf  = (u16*)alloc(1024ull * 128 * 2);
  u16* wihb_bf  = (u16*)alloc(1024ull * 128 * 2);
  u16* whhf_bf  = (u16*)alloc(1024ull * 256 * 2);
  u16* whhb_bf  = (u16*)alloc(1024ull * 256 * 2);
  u16* act_bf   = (u16*)alloc(100ull * 128 * 2);
  u16* wcT_bf   = (u16*)alloc(512ull * 512 * 2);
  u16* wp_bf    = (u16*)alloc(512ull * 1024 * 2);
  u16* wbd01_bf = (u16*)alloc(512ull * 1024 * 2);
  u16* wbdx_bf  = (u16*)alloc(512ull * 128 * 2);
  u16* dwih_bf  = (u16*)alloc(2048ull * 512 * 2);
  u16* dwhh_bf  = (u16*)alloc(2048ull * 512 * 2);
  u16* h2a_bf   = (u16*)alloc(100ull * 512 * 2);

  // --- all weight conversions in ONE launch ---
  CvtJobs cj{};
  int nb = 0, jn = 0;
  auto addjob = [&](const float* s, u16* d, int R, int C, int ld, int c0c, int tr) {
    cj.j[jn] = { s, d, R, C, ld, c0c, tr, nb };
    nb += (R * C + 255) / 256;
    jn++;
  };
  addjob(enc_emb, emb_bf, 2000, 128, 128, 0, 0);
  addjob(Wih_f, wihf_bf, 1024, 128, 128, 0, 0);
  addjob(Wih_b, wihb_bf, 1024, 128, 128, 0, 0);
  addjob(Whh_f, whhf_bf, 1024, 256, 256, 0, 0);
  addjob(Whh_b, whhb_bf, 1024, 256, 256, 0, 0);
  addjob(act_emb, act_bf, 100, 128, 128, 0, 0);
  addjob(W_c, wcT_bf, 512, 512, 512, 0, 1);   // transposed
  addjob(W_p, wp_bf, 512, 1024, 1024, 0, 0);
  addjob(Wbd_W, wbd01_bf, 512, 1024, 2944, 0, 0);
  addjob(Wbd_W, wbdx_bf, 512, 128, 2944, 2816, 0);
  addjob(dec_Wih, dwih_bf, 2048, 512, 512, 0, 0);
  addjob(dec_Whh, dwhh_bf, 2048, 512, 512, 0, 0);
  addjob(h2a_W, h2a_bf, 100, 512, 512, 0, 0);
  cj.njobs = jn;
  cvt_all<<<nb, 256, 0, stream>>>(cj);

  // --- fused bias prep + dec_init ---
  prep_small<<<(4708 + 128 * 512 + 255) / 256, 256, 0, stream>>>(
      bih_f, bhh_f, bias_f, bih_b, bhh_b, bias_b,
      Wbd_b, bwbd, h2a_b, bh2a, dec_bih, dec_bhh, bdecint,
      h0, c0, zin, qbuf, c_dec);
  wsum_build<<<1792, 256, 0, stream>>>(Wbd_W, Wsum);

  // --- projE tables ---
  {
    GemmArgs ge = {};
    ge.A = emb_bf; ge.lda = 128; ge.M = 2000; ge.W = wihf_bf; ge.ldw = 128;
    ge.N = 1024; ge.K = 128; ge.out = projE_f; ge.ldc = 1024;
    gemm_k<0><<<dim3(32, 16), 256, 0, stream>>>(ge);
    ge.W = wihb_bf; ge.out = projE_b;
    gemm_k<0><<<dim3(32, 16), 256, 0, stream>>>(ge);
  }

  // --- proj_act = act_emb @ Wbd_x^T + Wbd_b ---
  GemmArgs gp = {};
  gp.A = act_bf; gp.lda = 128; gp.M = 100; gp.W = wbdx_bf; gp.ldw = 128;
  gp.N = 512; gp.K = 128; gp.out = projact; gp.ldc = 512; gp.bias = bwbd;
  gemm_k<0><<<dim3(2, 8), 256, 0, stream>>>(gp);

  // --- env encode + hk_base ---
  env_encode<<<224, 256, 0, stream>>>(cur_env, ini_env, color_emb, pos_emb,
                                      ws_Wih, ws_Whh, ws_bih, ws_bhh, ctxcat);
  GemmArgs gb = {};
  gb.A = ctxcat; gb.lda = 896; gb.M = 128; gb.W = Wsum; gb.ldw = 896;
  gb.N = 512; gb.K = 896; gb.out = hkbase; gb.ldc = 512;
  gemm_k<0><<<dim3(2, 8), 256, 0, stream>>>(gb);

  // --- encoder: 128 sequential steps, 128-thread blocks ---
  for (int t = 0; t < 128; t++) {
    int cb = (t < 64) ? 0 : 2;
    int nbk = (t < 64) ? 256 : 128;
    enc_step3<<<nbk, 128, 0, stream>>>(t, cb, ins_tok, his_tok,
                                       projE_f, projE_b, whhf_bf, whhb_bf,
                                       bias_f, bias_b, h_enc, c_enc,
                                       insenc, hisenc);
  }

  // --- A_c = insenc @ W_c ---
  {
    GemmArgs ga = {};
    ga.A = insenc; ga.lda = 512; ga.M = 8192; ga.W = wcT_bf; ga.ldw = 512;
    ga.N = 512; ga.K = 512; ga.out = A_c; ga.ldc = 512;
    gemm_k<1><<<dim3(128, 8), 256, 0, stream>>>(ga);
  }

  // --- decoder: 5 dispatches/step ---
  for (int t = 0; t < 32; t++) {
    u16* zin_cur = zin + (size_t)(t & 1) * 128 * 1024;
    u16* zin_nxt = zin + (size_t)((t + 1) & 1) * 128 * 1024;
    attn1<<<128, 512, 0, stream>>>(A_c, insenc, qattn, qbuf);
    // u_p K-split: 128 blocks (2 K-halves x 64)
    up_split<<<dim3(4, 32), 256, 0, stream>>>(qbuf, wp_bf, u_p2);
    attn2<<<128, 512, 0, stream>>>(u_p2, hisenc, qattn);
    // hk -> 64 blocks
    GemmArgs gh = {};
    gh.A = qattn; gh.lda = 1024; gh.M = 128; gh.W = wbd01_bf; gh.ldw = 1024;
    gh.N = 512; gh.K = 1024; gh.out = zin_cur; gh.ldc = 1024;
    gh.hk_base = hkbase; gh.proj_act = projact; gh.actions = actions; gh.t = t;
    gemm32_k<2><<<dim3(4, 16), 256, 0, stream>>>(gh);
    // gates + fused cell: 256 blocks
    dec_gates_cell32<<<dim3(4, 64), 256, 0, stream>>>(
        zin_cur, dwih_bf, dwhh_bf, bdecint, c_dec, zin_nxt, qbuf, outs, t);
  }

  // --- logits (f32 out): 512 blocks ---
  GemmArgs gl = {};
  gl.A = outs; gl.lda = 512; gl.M = 4096; gl.W = h2a_bf; gl.ldw = 512;
  gl.N = 100; gl.K = 512; gl.out = d_out; gl.ldc = 100; gl.bias = bh2a;
  gemm32_k<0><<<dim3(128, 4), 256, 0, stream>>>(gl);
}